// Round 11
// baseline (62.722 us; speedup 1.0000x reference)
//
#include <hip/hip_runtime.h>

#define NATOMS 8192
#define NMOLS  256
#define APM    32
#define EPM    61
#define D      64
#define FIN    16
#define SE     72   // bf16 elems per LDS state row (144B)

typedef __bf16 bf16x8 __attribute__((ext_vector_type(8)));
typedef float  f32x4  __attribute__((ext_vector_type(4)));

#define MFMA_BF16(a, b, c) __builtin_amdgcn_mfma_f32_16x16x32_bf16((a), (b), (c), 0, 0, 0)

__device__ __forceinline__ ushort f2bf(float x) {   // RNE f32 -> bf16
    uint u = __float_as_uint(x);
    u += 0x7fffu + ((u >> 16) & 1u);
    return (ushort)(u >> 16);
}
__device__ __forceinline__ float bf2f(ushort h) {
    return __uint_as_float(((uint)h) << 16);
}
__device__ __forceinline__ void split2(float x, ushort& h, ushort& l) {
    ushort hh = f2bf(x);
    h = hh;
    l = f2bf(x - bf2f(hh));
}
// tanh(x) = 1 - 2/(exp(2x)+1); exp2-based, saturates correctly at +-inf
__device__ __forceinline__ float fast_tanh(float x) {
    float e = __builtin_amdgcn_exp2f(x * 2.885390081777926f);   // exp(2x)
    float r = __builtin_amdgcn_rcpf(e + 1.0f);
    return __builtin_fmaf(-2.0f, r, 1.0f);
}

union FragU { ushort u[8]; bf16x8 v; };

// split-bf16 step with SPLIT lo chains: H += Ah*Wh ; La += Al*Wh ; Lb += Ah*Wl
__device__ __forceinline__ void mfma3s(const ushort* pH, const ushort* pL, int o,
                                       bf16x8 wH, bf16x8 wL,
                                       f32x4& H, f32x4& La, f32x4& Lb) {
    bf16x8 ah = *(const bf16x8*)(pH + o);
    bf16x8 al = *(const bf16x8*)(pL + o);
    H  = MFMA_BF16(ah, wH, H);
    La = MFMA_BF16(al, wH, La);
    Lb = MFMA_BF16(ah, wL, Lb);
}

__global__ __launch_bounds__(512, 2) void graphnet_kernel(
    const float* __restrict__ atoms,
    const float* __restrict__ adj,
    const int*   __restrict__ left,
    const int*   __restrict__ right,
    const float* __restrict__ Wfe, const float* __restrict__ bfe,
    const float* __restrict__ Wfv, const float* __restrict__ bfv,
    const float* __restrict__ Wfu, const float* __restrict__ bfu,
    const float* __restrict__ Wpe, const float* __restrict__ bpe,
    const float* __restrict__ Wpv, const float* __restrict__ bpv,
    const float* __restrict__ Wpu, const float* __restrict__ bpu,
    float* __restrict__ out)
{
    __shared__ __align__(16) ushort heH[2][64 * SE], heL[2][64 * SE];  // dbuf; rows 61-63 zero
    __shared__ __align__(16) ushort hvH[2][APM * SE], hvL[2][APM * SE];
    __shared__ __align__(16) ushort huH[D], huL[D];
    __shared__ float huF[D], hu0F[D];
    __shared__ float apm_s[FIN];
    __shared__ float parte[4][D];
    __shared__ float part2[2][D];
    __shared__ float hebar[D];
    __shared__ float phiu_part[8][D];
    __shared__ int   lloc[EPM], rloc[EPM];
    __shared__ int   inc[APM][4];              // padded with edge 63 (zero row)

    const int tid  = threadIdx.x;
    const int lane = tid & 63;
    const int w    = tid >> 6;                 // wave 0..7
    const int nt   = w & 3;                    // N-tile (16-col slice)
    const int mt2  = w >> 2;                   // 0..1
    const int cb   = __builtin_amdgcn_readfirstlane(nt) * 16;
    const int lr   = lane & 15;
    const int kb   = lane >> 4;
    const int m    = blockIdx.x;

    // ---------------- init: all LDS writes, no intra-init barriers ----------------
    if (tid < EPM) {
        lloc[tid] = left [m * EPM + tid] - m * APM;
        rloc[tid] = right[m * EPM + tid] - m * APM;
    }
    // incidence lists from wave-uniform global reads (padded to 4 with zero-row 63)
    if (tid < APM) {
        int dg = 0;
        for (int e = 0; e < EPM; ++e) {
            int gl = left [m * EPM + e] - m * APM;   // thread-invariant -> s_load
            int gr = right[m * EPM + e] - m * APM;
            if (gl == tid) inc[tid][dg++] = e;
            if (gr == tid) inc[tid][dg++] = e;
        }
        for (int j = dg; j < 4; ++j) inc[tid][j] = 63;
    }
    if (tid < FIN) {
        float s = 0.f;
        for (int a = 0; a < APM; ++a) s += atoms[(m * APM + a) * FIN + tid];
        apm_s[tid] = s;
    }
    // h_v init (atom row wave-uniform -> scalar loads)
    #pragma unroll
    for (int i = 0; i < 4; ++i) {
        int idx = tid + 512 * i;               // 0..2047
        int a = idx >> 6, c = idx & 63;
        float acc = bfv[c];
        #pragma unroll
        for (int f = 0; f < FIN; ++f)
            acc += atoms[(m * APM + a) * FIN + f] * Wfv[f * D + c];
        float t = fast_tanh(acc);
        ushort h, l; split2(t, h, l);
        hvH[0][a * SE + c] = h; hvL[0][a * SE + c] = l;
    }
    // h_e init (+ zero pad rows 61..63 in BOTH buffers)
    #pragma unroll
    for (int i = 0; i < 8; ++i) {
        int idx = tid + 512 * i;               // 0..4095
        int e = idx >> 6, c = idx & 63;        // e wave-uniform
        float t = 0.f;
        if (e < EPM) {
            int gl = left [m * EPM + e];       // thread-invariant -> s_load
            int gr = right[m * EPM + e];
            float bo = adj[(size_t)gl * NATOMS + gr];
            t = fast_tanh(bo * Wfe[c] + bfe[c]);
        }
        ushort h, l; split2(t, h, l);
        heH[0][e * SE + c] = h; heL[0][e * SE + c] = l;
        if (e >= EPM) { heH[1][e * SE + c] = 0; heL[1][e * SE + c] = 0; }
    }

    // ---------------- persistent weight fragments (s=2,3 transient below) ----------------
    FragU feH[8], feL[8], fvH[8], fvL[8];
    #pragma unroll
    for (int s = 0; s < 8; ++s) {
        if (s == 2 || s == 3) continue;        // constant blocks folded in precompute
        #pragma unroll
        for (int j = 0; j < 8; ++j) {
            split2(Wpe[(s * 32 + kb * 8 + j) * D + cb + lr], feH[s].u[j], feL[s].u[j]);
            split2(Wpv[(s * 32 + kb * 8 + j) * D + cb + lr], fvH[s].u[j], fvL[s].u[j]);
        }
    }
    float wpu_reg[32];
    #pragma unroll
    for (int kk = 0; kk < 32; ++kk)
        wpu_reg[kk] = Wpu[(w * 32 + kk) * D + lane];
    const float bias_e = bpe[cb + lr];
    const float w5_e   = Wpe[4 * D * D + cb + lr];
    const float bias_v = bpv[cb + lr];
    const float bpu_l  = bpu[lane];

    __syncthreads();                                               // B: all init visible

    // h_u: redundantly in registers per wave (lane = feature)
    float hu_val;
    {
        float acc = bfu[lane];
        #pragma unroll
        for (int f = 0; f < FIN; ++f) acc += apm_s[f] * Wfu[f * D + lane];
        hu_val = fast_tanh(acc);
        if (w == 7) {
            huF[lane] = hu_val; hu0F[lane] = hu_val;
            split2(hu_val, huH[lane], huL[lane]);
        }
    }

    const int col  = cb + lr;
    const int e0   = mt2 * 16 + lr;
    const int e1   = e0 + 32;
    const int ec1  = (e1 < EPM) ? e1 : EPM - 1;
    const int la0  = lloc[e0],  ra0 = rloc[e0];
    const int la1  = lloc[ec1], ra1 = rloc[ec1];
    const int ofk  = kb * 8;
    const int arow = mt2 * 16 + lr;
    const int ie0 = inc[arow][0], ie1 = inc[arow][1];
    const int ie2 = inc[arow][2], ie3 = inc[arow][3];

    // ---------------- loop-invariant contributions (he0@W2, hv0@V2 + biases) ----------------
    f32x4 cE0 = {bias_e, bias_e, bias_e, bias_e};
    f32x4 cE1 = cE0;
    f32x4 cV  = {bias_v, bias_v, bias_v, bias_v};
    {
        FragU w2h, w2l, w3h, w3l, v2h, v2l, v3h, v3l;
        #pragma unroll
        for (int j = 0; j < 8; ++j) {
            split2(Wpe[(2 * 32 + kb * 8 + j) * D + cb + lr], w2h.u[j], w2l.u[j]);
            split2(Wpe[(3 * 32 + kb * 8 + j) * D + cb + lr], w3h.u[j], w3l.u[j]);
            split2(Wpv[(2 * 32 + kb * 8 + j) * D + cb + lr], v2h.u[j], v2l.u[j]);
            split2(Wpv[(3 * 32 + kb * 8 + j) * D + cb + lr], v3h.u[j], v3l.u[j]);
        }
        f32x4 z0 = {0,0,0,0}, z1 = {0,0,0,0}, z2 = {0,0,0,0},
              z3 = {0,0,0,0}, z4 = {0,0,0,0}, z5 = {0,0,0,0};
        mfma3s(heH[0] + e0*SE,  heL[0] + e0*SE,  ofk,      w2h.v, w2l.v, cE0, z0, z1);
        mfma3s(heH[0] + e1*SE,  heL[0] + e1*SE,  ofk,      w2h.v, w2l.v, cE1, z2, z3);
        mfma3s(heH[0] + e0*SE,  heL[0] + e0*SE,  32 + ofk, w3h.v, w3l.v, cE0, z0, z1);
        mfma3s(heH[0] + e1*SE,  heL[0] + e1*SE,  32 + ofk, w3h.v, w3l.v, cE1, z2, z3);
        mfma3s(hvH[0] + arow*SE, hvL[0] + arow*SE, ofk,      v2h.v, v2l.v, cV, z4, z5);
        mfma3s(hvH[0] + arow*SE, hvL[0] + arow*SE, 32 + ofk, v3h.v, v3l.v, cV, z4, z5);
        cE0 += z0 + z1; cE1 += z2 + z3; cV += z4 + z5;
    }

    f32x4 aH0, aL0a, aL0b, aH1, aL1a, aL1b;

    // phi_e MFMA issue: 12 units (he0 term folded into cE0/cE1). NO sched_barrier.
#define PHIE_ISSUE(HC, LC, VHC, VLC)                                                        \
    aH0 = cE0; aL0a = (f32x4){0,0,0,0}; aL0b = (f32x4){0,0,0,0};                            \
    aH1 = cE1; aL1a = (f32x4){0,0,0,0}; aL1b = (f32x4){0,0,0,0};                            \
    mfma3s((HC) + e0*SE,   (LC) + e0*SE,   ofk,      feH[0].v, feL[0].v, aH0, aL0a, aL0b);  \
    mfma3s((HC) + e1*SE,   (LC) + e1*SE,   ofk,      feH[0].v, feL[0].v, aH1, aL1a, aL1b);  \
    mfma3s((HC) + e0*SE,   (LC) + e0*SE,   32 + ofk, feH[1].v, feL[1].v, aH0, aL0a, aL0b);  \
    mfma3s((HC) + e1*SE,   (LC) + e1*SE,   32 + ofk, feH[1].v, feL[1].v, aH1, aL1a, aL1b);  \
    mfma3s((VHC) + la0*SE, (VLC) + la0*SE, ofk,      feH[4].v, feL[4].v, aH0, aL0a, aL0b);  \
    mfma3s((VHC) + la1*SE, (VLC) + la1*SE, ofk,      feH[4].v, feL[4].v, aH1, aL1a, aL1b);  \
    mfma3s((VHC) + la0*SE, (VLC) + la0*SE, 32 + ofk, feH[5].v, feL[5].v, aH0, aL0a, aL0b);  \
    mfma3s((VHC) + la1*SE, (VLC) + la1*SE, 32 + ofk, feH[5].v, feL[5].v, aH1, aL1a, aL1b);  \
    mfma3s((VHC) + ra0*SE, (VLC) + ra0*SE, ofk,      feH[6].v, feL[6].v, aH0, aL0a, aL0b);  \
    mfma3s((VHC) + ra1*SE, (VLC) + ra1*SE, ofk,      feH[6].v, feL[6].v, aH1, aL1a, aL1b);  \
    mfma3s((VHC) + ra0*SE, (VLC) + ra0*SE, 32 + ofk, feH[7].v, feL[7].v, aH0, aL0a, aL0b);  \
    mfma3s((VHC) + ra1*SE, (VLC) + ra1*SE, 32 + ofk, feH[7].v, feL[7].v, aH1, aL1a, aL1b);

    int cur = 0;
    PHIE_ISSUE(heH[0], heL[0], hvH[0], hvL[0]);    // prologue issue for it=0

    // ---------------- 3 message-passing iterations (rotated schedule) ----------------
    for (int it = 0; it < 3; ++it) {
        const int nxt = cur ^ 1;

        // ---- deferred hu finalize (phiu_part D-guarded from prev iter),
        //      hides under the in-flight phi_e MFMAs ----
        if (it > 0) {
            float t = bpu_l;
            #pragma unroll
            for (int w8 = 0; w8 < 8; ++w8) t += phiu_part[w8][lane];
            hu_val = fast_tanh(t);
            if (w == 7) {
                huF[lane] = hu_val;
                split2(hu_val, huH[lane], huL[lane]);
            }
        }
        // u_e = sum(h_u): register butterfly
        float uev = hu_val;
        #pragma unroll
        for (int off = 32; off; off >>= 1) uev += __shfl_xor(uev, off, 64);

        // ---- phi_e epilogue (MFMAs issued last iteration / prologue) ----
        float out0[4], out1[4]; float ps0 = 0.f, ps1 = 0.f;
        #pragma unroll
        for (int r = 0; r < 4; ++r) {
            float t0 = fast_tanh(aH0[r] + aL0a[r] + aL0b[r] + uev * w5_e);
            float t1 = fast_tanh(aH1[r] + aL1a[r] + aL1b[r] + uev * w5_e);
            out0[r] = t0; out1[r] = t1;
            ps0 += t0;
            if (32 + mt2 * 16 + kb * 4 + r < EPM) ps1 += t1;
        }

        if (it == 2) {                         // final: write output, done
            #pragma unroll
            for (int r = 0; r < 4; ++r) {
                int g0 = mt2 * 16 + kb * 4 + r;
                out[((size_t)(m * EPM + g0)) * D + col] = out0[r];
                int g1 = g0 + 32;
                if (g1 < EPM) out[((size_t)(m * EPM + g1)) * D + col] = out1[r];
            }
            return;
        }

        ps0 += __shfl_xor(ps0, 16, 64); ps0 += __shfl_xor(ps0, 32, 64);
        ps1 += __shfl_xor(ps1, 16, 64); ps1 += __shfl_xor(ps1, 32, 64);

        #pragma unroll
        for (int r = 0; r < 4; ++r) {
            int g0 = mt2 * 16 + kb * 4 + r;
            split2(out0[r], heH[nxt][g0 * SE + col], heL[nxt][g0 * SE + col]);
            int g1 = g0 + 32;
            if (g1 < EPM)
                split2(out1[r], heH[nxt][g1 * SE + col], heL[nxt][g1 * SE + col]);
        }
        if (kb == 0) { parte[mt2][col] = ps0; parte[2 + mt2][col] = ps1; }
        __syncthreads();                                           // A: new he ready

        // ---- phi_v: 12 units, hbi inlined via linearity; chains split 6+6 ----
        const ushort* hvHc = hvH[cur]; const ushort* hvLc = hvL[cur];
        const ushort* heHn = heH[nxt]; const ushort* heLn = heL[nxt];

        f32x4 vH  = cV,        vLa  = {0,0,0,0}, vLb  = {0,0,0,0};
        f32x4 vH2 = {0,0,0,0}, vLa2 = {0,0,0,0}, vLb2 = {0,0,0,0};
        mfma3s(hvHc + arow*SE, hvLc + arow*SE, ofk,      fvH[0].v, fvL[0].v, vH, vLa, vLb);
        mfma3s(hvHc + arow*SE, hvLc + arow*SE, 32 + ofk, fvH[1].v, fvL[1].v, vH, vLa, vLb);
        mfma3s(heHn + ie0*SE, heLn + ie0*SE, ofk,      fvH[4].v, fvL[4].v, vH, vLa, vLb);
        mfma3s(heHn + ie0*SE, heLn + ie0*SE, 32 + ofk, fvH[5].v, fvL[5].v, vH, vLa, vLb);
        mfma3s(heHn + ie1*SE, heLn + ie1*SE, ofk,      fvH[4].v, fvL[4].v, vH, vLa, vLb);
        mfma3s(heHn + ie1*SE, heLn + ie1*SE, 32 + ofk, fvH[5].v, fvL[5].v, vH, vLa, vLb);
        mfma3s(heHn + ie2*SE, heLn + ie2*SE, ofk,      fvH[4].v, fvL[4].v, vH2, vLa2, vLb2);
        mfma3s(heHn + ie2*SE, heLn + ie2*SE, 32 + ofk, fvH[5].v, fvL[5].v, vH2, vLa2, vLb2);
        mfma3s(heHn + ie3*SE, heLn + ie3*SE, ofk,      fvH[4].v, fvL[4].v, vH2, vLa2, vLb2);
        mfma3s(heHn + ie3*SE, heLn + ie3*SE, 32 + ofk, fvH[5].v, fvL[5].v, vH2, vLa2, vLb2);
        mfma3s(huH, huL, ofk,      fvH[6].v, fvL[6].v, vH2, vLa2, vLb2);
        mfma3s(huH, huL, 32 + ofk, fvH[7].v, fvL[7].v, vH2, vLa2, vLb2);

        if (tid < D)   // hebar reduce (readers are post-C), under the MFMA block
            hebar[tid] = parte[0][tid] + parte[1][tid] + parte[2][tid] + parte[3][tid];

        float outv2[4]; float ps2 = 0.f;
        #pragma unroll
        for (int r = 0; r < 4; ++r) {
            float t = fast_tanh((vH[r] + vH2[r]) + (vLa[r] + vLa2[r]) + (vLb[r] + vLb2[r]));
            outv2[r] = t; ps2 += t;
        }
        ps2 += __shfl_xor(ps2, 16, 64); ps2 += __shfl_xor(ps2, 32, 64);
        #pragma unroll
        for (int r = 0; r < 4; ++r) {
            int g = mt2 * 16 + kb * 4 + r;
            split2(outv2[r], hvH[nxt][g * SE + col], hvL[nxt][g * SE + col]);
        }
        if (kb == 0) part2[mt2][col] = ps2;
        __syncthreads();                                           // C: hv' + part2 ready

        // ---- issue NEXT iteration's phi_e MFMAs (inputs ready at A/C);
        //      phi_u + barrier D then hide under their execution ----
        PHIE_ISSUE(heH[nxt], heL[nxt], hvH[nxt], hvL[nxt]);

        // ---- phi_u partials: wave w owns K rows [w*32, w*32+32) ----
        {
            const int b  = w >> 1;             // source block (wave-uniform)
            const int k0 = (w & 1) * 32;
            float s = 0.f;
            #pragma unroll
            for (int kk = 0; kk < 32; ++kk) {
                int k = k0 + kk;
                float x = (b == 0) ? huF[k] : (b == 1) ? hu0F[k]
                        : (b == 2) ? hebar[k] : (part2[0][k] + part2[1][k]);
                s += x * wpu_reg[kk];
            }
            phiu_part[w][lane] = s;
        }
        __syncthreads();                                           // D: phiu_part ready
        cur = nxt;                             // hu finalize deferred to next iter
    }
}

extern "C" void kernel_launch(void* const* d_in, const int* in_sizes, int n_in,
                              void* d_out, int out_size, void* d_ws, size_t ws_size,
                              hipStream_t stream) {
    const float* atoms = (const float*)d_in[0];
    const float* adj   = (const float*)d_in[1];
    const int*   left  = (const int*)  d_in[2];
    const int*   right = (const int*)  d_in[3];
    const float* Wfe = (const float*)d_in[6];
    const float* bfe = (const float*)d_in[7];
    const float* Wfv = (const float*)d_in[8];
    const float* bfv = (const float*)d_in[9];
    const float* Wfu = (const float*)d_in[10];
    const float* bfu = (const float*)d_in[11];
    const float* Wpe = (const float*)d_in[12];
    const float* bpe = (const float*)d_in[13];
    const float* Wpv = (const float*)d_in[14];
    const float* bpv = (const float*)d_in[15];
    const float* Wpu = (const float*)d_in[16];
    const float* bpu = (const float*)d_in[17];

    graphnet_kernel<<<dim3(NMOLS), dim3(512), 0, stream>>>(
        atoms, adj, left, right,
        Wfe, bfe, Wfv, bfv, Wfu, bfu,
        Wpe, bpe, Wpv, bpv, Wpu, bpu,
        (float*)d_out);
}

// Round 12
// 34.931 us; speedup vs baseline: 1.7956x; 1.7956x over previous
//
#include <hip/hip_runtime.h>

#define NATOMS 8192
#define NMOLS  256
#define APM    32
#define EPM    61
#define D      64
#define FIN    16
#define SE     72   // bf16 elems per LDS state row (144B)

typedef __bf16 bf16x8 __attribute__((ext_vector_type(8)));
typedef float  f32x4  __attribute__((ext_vector_type(4)));

#define MFMA_BF16(a, b, c) __builtin_amdgcn_mfma_f32_16x16x32_bf16((a), (b), (c), 0, 0, 0)

__device__ __forceinline__ ushort f2bf(float x) {   // RNE f32 -> bf16
    uint u = __float_as_uint(x);
    u += 0x7fffu + ((u >> 16) & 1u);
    return (ushort)(u >> 16);
}
__device__ __forceinline__ float bf2f(ushort h) {
    return __uint_as_float(((uint)h) << 16);
}
__device__ __forceinline__ void split2(float x, ushort& h, ushort& l) {
    ushort hh = f2bf(x);
    h = hh;
    l = f2bf(x - bf2f(hh));
}
// tanh(x) = 1 - 2/(exp(2x)+1); exp2-based, saturates correctly at +-inf
__device__ __forceinline__ float fast_tanh(float x) {
    float e = __builtin_amdgcn_exp2f(x * 2.885390081777926f);   // exp(2x)
    float r = __builtin_amdgcn_rcpf(e + 1.0f);
    return __builtin_fmaf(-2.0f, r, 1.0f);
}

union FragU { ushort u[8]; bf16x8 v; };

// split-bf16 step with SPLIT lo chains: H += Ah*Wh ; La += Al*Wh ; Lb += Ah*Wl
__device__ __forceinline__ void mfma3s(const ushort* pH, const ushort* pL, int o,
                                       bf16x8 wH, bf16x8 wL,
                                       f32x4& H, f32x4& La, f32x4& Lb) {
    bf16x8 ah = *(const bf16x8*)(pH + o);
    bf16x8 al = *(const bf16x8*)(pL + o);
    H  = MFMA_BF16(ah, wH, H);
    La = MFMA_BF16(al, wH, La);
    Lb = MFMA_BF16(ah, wL, Lb);
}

__global__ __launch_bounds__(512, 2) void graphnet_kernel(
    const float* __restrict__ atoms,
    const float* __restrict__ adj,
    const int*   __restrict__ left,
    const int*   __restrict__ right,
    const float* __restrict__ Wfe, const float* __restrict__ bfe,
    const float* __restrict__ Wfv, const float* __restrict__ bfv,
    const float* __restrict__ Wfu, const float* __restrict__ bfu,
    const float* __restrict__ Wpe, const float* __restrict__ bpe,
    const float* __restrict__ Wpv, const float* __restrict__ bpv,
    const float* __restrict__ Wpu, const float* __restrict__ bpu,
    float* __restrict__ out)
{
    __shared__ __align__(16) ushort heH[2][64 * SE], heL[2][64 * SE];  // dbuf; rows 61-63 zero
    __shared__ __align__(16) ushort hvH[2][APM * SE], hvL[2][APM * SE];
    __shared__ __align__(16) ushort huH[D], huL[D];
    __shared__ float huF[D], hu0F[D];
    __shared__ float apm_s[FIN];
    __shared__ float parte[4][D];
    __shared__ float part2[2][D];
    __shared__ float hebar[D];
    __shared__ float phiu_part[8][D];
    __shared__ int   lloc[EPM], rloc[EPM];
    __shared__ int   inc[APM][4];              // padded with edge 63 (zero row)

    const int tid  = threadIdx.x;
    const int lane = tid & 63;
    const int w    = tid >> 6;                 // wave 0..7
    const int nt   = w & 3;                    // N-tile (16-col slice)
    const int mt2  = w >> 2;                   // 0..1
    const int cb   = __builtin_amdgcn_readfirstlane(nt) * 16;
    const int lr   = lane & 15;
    const int kb   = lane >> 4;
    const int m    = blockIdx.x;

    // ---------------- init: all LDS writes, no intra-init barriers ----------------
    if (tid < EPM) {
        lloc[tid] = left [m * EPM + tid] - m * APM;
        rloc[tid] = right[m * EPM + tid] - m * APM;
    }
    // incidence lists from wave-uniform global reads (padded to 4 with zero-row 63)
    if (tid < APM) {
        int dg = 0;
        for (int e = 0; e < EPM; ++e) {
            int gl = left [m * EPM + e] - m * APM;   // thread-invariant -> s_load
            int gr = right[m * EPM + e] - m * APM;
            if (gl == tid) inc[tid][dg++] = e;
            if (gr == tid) inc[tid][dg++] = e;
        }
        for (int j = dg; j < 4; ++j) inc[tid][j] = 63;
    }
    if (tid < FIN) {
        float s = 0.f;
        for (int a = 0; a < APM; ++a) s += atoms[(m * APM + a) * FIN + tid];
        apm_s[tid] = s;
    }
    // h_v init (atom row wave-uniform -> scalar loads)
    #pragma unroll
    for (int i = 0; i < 4; ++i) {
        int idx = tid + 512 * i;               // 0..2047
        int a = idx >> 6, c = idx & 63;
        float acc = bfv[c];
        #pragma unroll
        for (int f = 0; f < FIN; ++f)
            acc += atoms[(m * APM + a) * FIN + f] * Wfv[f * D + c];
        float t = fast_tanh(acc);
        ushort h, l; split2(t, h, l);
        hvH[0][a * SE + c] = h; hvL[0][a * SE + c] = l;
    }
    // h_e init (+ zero pad rows 61..63 in BOTH buffers)
    #pragma unroll
    for (int i = 0; i < 8; ++i) {
        int idx = tid + 512 * i;               // 0..4095
        int e = idx >> 6, c = idx & 63;        // e wave-uniform
        float t = 0.f;
        if (e < EPM) {
            int gl = left [m * EPM + e];       // thread-invariant -> s_load
            int gr = right[m * EPM + e];
            float bo = adj[(size_t)gl * NATOMS + gr];
            t = fast_tanh(bo * Wfe[c] + bfe[c]);
        }
        ushort h, l; split2(t, h, l);
        heH[0][e * SE + c] = h; heL[0][e * SE + c] = l;
        if (e >= EPM) { heH[1][e * SE + c] = 0; heL[1][e * SE + c] = 0; }
    }

    // ---------------- persistent weight fragments (s=2,3 transient below) ----------------
    FragU feH[8], feL[8], fvH[8], fvL[8];
    #pragma unroll
    for (int s = 0; s < 8; ++s) {
        if (s == 2 || s == 3) continue;        // constant blocks folded in precompute
        #pragma unroll
        for (int j = 0; j < 8; ++j) {
            split2(Wpe[(s * 32 + kb * 8 + j) * D + cb + lr], feH[s].u[j], feL[s].u[j]);
            split2(Wpv[(s * 32 + kb * 8 + j) * D + cb + lr], fvH[s].u[j], fvL[s].u[j]);
        }
    }
    float wpu_reg[32];
    #pragma unroll
    for (int kk = 0; kk < 32; ++kk)
        wpu_reg[kk] = Wpu[(w * 32 + kk) * D + lane];
    const float bias_e = bpe[cb + lr];
    const float w5_e   = Wpe[4 * D * D + cb + lr];
    const float bias_v = bpv[cb + lr];
    const float bpu_l  = bpu[lane];

    __syncthreads();                                               // B: all init visible

    // h_u: redundantly in registers per wave (lane = feature)
    float hu_val;
    {
        float acc = bfu[lane];
        #pragma unroll
        for (int f = 0; f < FIN; ++f) acc += apm_s[f] * Wfu[f * D + lane];
        hu_val = fast_tanh(acc);
        if (w == 7) {
            huF[lane] = hu_val; hu0F[lane] = hu_val;
            split2(hu_val, huH[lane], huL[lane]);
        }
    }

    const int col  = cb + lr;
    const int e0   = mt2 * 16 + lr;
    const int e1   = e0 + 32;
    const int ec1  = (e1 < EPM) ? e1 : EPM - 1;
    const int la0  = lloc[e0],  ra0 = rloc[e0];
    const int la1  = lloc[ec1], ra1 = rloc[ec1];
    const int ofk  = kb * 8;
    const int arow = mt2 * 16 + lr;
    const int ie0 = inc[arow][0], ie1 = inc[arow][1];
    const int ie2 = inc[arow][2], ie3 = inc[arow][3];

    // ---------------- loop-invariant contributions (he0@W2, hv0@V2 + biases) ----------------
    f32x4 cE0 = {bias_e, bias_e, bias_e, bias_e};
    f32x4 cE1 = cE0;
    f32x4 cV  = {bias_v, bias_v, bias_v, bias_v};
    {
        FragU w2h, w2l, w3h, w3l, v2h, v2l, v3h, v3l;
        #pragma unroll
        for (int j = 0; j < 8; ++j) {
            split2(Wpe[(2 * 32 + kb * 8 + j) * D + cb + lr], w2h.u[j], w2l.u[j]);
            split2(Wpe[(3 * 32 + kb * 8 + j) * D + cb + lr], w3h.u[j], w3l.u[j]);
            split2(Wpv[(2 * 32 + kb * 8 + j) * D + cb + lr], v2h.u[j], v2l.u[j]);
            split2(Wpv[(3 * 32 + kb * 8 + j) * D + cb + lr], v3h.u[j], v3l.u[j]);
        }
        f32x4 z0 = {0,0,0,0}, z1 = {0,0,0,0}, z2 = {0,0,0,0},
              z3 = {0,0,0,0}, z4 = {0,0,0,0}, z5 = {0,0,0,0};
        mfma3s(heH[0] + e0*SE,  heL[0] + e0*SE,  ofk,      w2h.v, w2l.v, cE0, z0, z1);
        mfma3s(heH[0] + e1*SE,  heL[0] + e1*SE,  ofk,      w2h.v, w2l.v, cE1, z2, z3);
        mfma3s(heH[0] + e0*SE,  heL[0] + e0*SE,  32 + ofk, w3h.v, w3l.v, cE0, z0, z1);
        mfma3s(heH[0] + e1*SE,  heL[0] + e1*SE,  32 + ofk, w3h.v, w3l.v, cE1, z2, z3);
        mfma3s(hvH[0] + arow*SE, hvL[0] + arow*SE, ofk,      v2h.v, v2l.v, cV, z4, z5);
        mfma3s(hvH[0] + arow*SE, hvL[0] + arow*SE, 32 + ofk, v3h.v, v3l.v, cV, z4, z5);
        cE0 += z0 + z1; cE1 += z2 + z3; cV += z4 + z5;
    }

    int cur = 0;
    // ---------------- 3 message-passing iterations, 3 barriers each ----------------
    for (int it = 0; it < 3; ++it) {
        const ushort* heHc = heH[cur]; const ushort* heLc = heL[cur];
        const ushort* hvHc = hvH[cur]; const ushort* hvLc = hvL[cur];

        // ---- phi_e MFMA block: 12 units (he0 term folded into cE0/cE1) ----
        f32x4 aH0 = cE0, aL0a = {0,0,0,0}, aL0b = {0,0,0,0};
        f32x4 aH1 = cE1, aL1a = {0,0,0,0}, aL1b = {0,0,0,0};
        mfma3s(heHc + e0*SE,  heLc + e0*SE,  ofk,      feH[0].v, feL[0].v, aH0, aL0a, aL0b);
        mfma3s(heHc + e1*SE,  heLc + e1*SE,  ofk,      feH[0].v, feL[0].v, aH1, aL1a, aL1b);
        mfma3s(heHc + e0*SE,  heLc + e0*SE,  32 + ofk, feH[1].v, feL[1].v, aH0, aL0a, aL0b);
        mfma3s(heHc + e1*SE,  heLc + e1*SE,  32 + ofk, feH[1].v, feL[1].v, aH1, aL1a, aL1b);
        mfma3s(hvHc + la0*SE, hvLc + la0*SE, ofk,      feH[4].v, feL[4].v, aH0, aL0a, aL0b);
        mfma3s(hvHc + la1*SE, hvLc + la1*SE, ofk,      feH[4].v, feL[4].v, aH1, aL1a, aL1b);
        mfma3s(hvHc + la0*SE, hvLc + la0*SE, 32 + ofk, feH[5].v, feL[5].v, aH0, aL0a, aL0b);
        mfma3s(hvHc + la1*SE, hvLc + la1*SE, 32 + ofk, feH[5].v, feL[5].v, aH1, aL1a, aL1b);
        mfma3s(hvHc + ra0*SE, hvLc + ra0*SE, ofk,      feH[6].v, feL[6].v, aH0, aL0a, aL0b);
        mfma3s(hvHc + ra1*SE, hvLc + ra1*SE, ofk,      feH[6].v, feL[6].v, aH1, aL1a, aL1b);
        mfma3s(hvHc + ra0*SE, hvLc + ra0*SE, 32 + ofk, feH[7].v, feL[7].v, aH0, aL0a, aL0b);
        mfma3s(hvHc + ra1*SE, hvLc + ra1*SE, 32 + ofk, feH[7].v, feL[7].v, aH1, aL1a, aL1b);

        // ---- deferred hu finalize (phiu_part D-guarded from prev iter),
        //      hidden under the MFMA block above ----
        if (it > 0) {
            float t = bpu_l;
            #pragma unroll
            for (int w8 = 0; w8 < 8; ++w8) t += phiu_part[w8][lane];
            hu_val = fast_tanh(t);
            if (w == 7) {
                huF[lane] = hu_val;
                split2(hu_val, huH[lane], huL[lane]);
            }
        }
        // u_e = sum(h_u): register butterfly
        float uev = hu_val;
        #pragma unroll
        for (int off = 32; off; off >>= 1) uev += __shfl_xor(uev, off, 64);

        // ---- phi_e epilogue (bias folded into constants) ----
        float out0[4], out1[4]; float ps0 = 0.f, ps1 = 0.f;
        #pragma unroll
        for (int r = 0; r < 4; ++r) {
            float t0 = fast_tanh(aH0[r] + aL0a[r] + aL0b[r] + uev * w5_e);
            float t1 = fast_tanh(aH1[r] + aL1a[r] + aL1b[r] + uev * w5_e);
            out0[r] = t0; out1[r] = t1;
            ps0 += t0;
            if (32 + mt2 * 16 + kb * 4 + r < EPM) ps1 += t1;
        }

        if (it == 2) {                         // final: write output, done
            #pragma unroll
            for (int r = 0; r < 4; ++r) {
                int g0 = mt2 * 16 + kb * 4 + r;
                out[((size_t)(m * EPM + g0)) * D + col] = out0[r];
                int g1 = g0 + 32;
                if (g1 < EPM) out[((size_t)(m * EPM + g1)) * D + col] = out1[r];
            }
            return;
        }

        ps0 += __shfl_xor(ps0, 16, 64); ps0 += __shfl_xor(ps0, 32, 64);
        ps1 += __shfl_xor(ps1, 16, 64); ps1 += __shfl_xor(ps1, 32, 64);

        const int nxt = cur ^ 1;
        #pragma unroll
        for (int r = 0; r < 4; ++r) {
            int g0 = mt2 * 16 + kb * 4 + r;
            split2(out0[r], heH[nxt][g0 * SE + col], heL[nxt][g0 * SE + col]);
            int g1 = g0 + 32;
            if (g1 < EPM)
                split2(out1[r], heH[nxt][g1 * SE + col], heL[nxt][g1 * SE + col]);
        }
        if (kb == 0) { parte[mt2][col] = ps0; parte[2 + mt2][col] = ps1; }
        __syncthreads();                                           // A: new he ready

        // ---- phi_v: 12 units, hbi inlined via linearity; chains split 6+6 ----
        const ushort* heHn = heH[nxt]; const ushort* heLn = heL[nxt];

        f32x4 vH  = cV,        vLa  = {0,0,0,0}, vLb  = {0,0,0,0};
        f32x4 vH2 = {0,0,0,0}, vLa2 = {0,0,0,0}, vLb2 = {0,0,0,0};
        mfma3s(hvHc + arow*SE, hvLc + arow*SE, ofk,      fvH[0].v, fvL[0].v, vH, vLa, vLb);
        mfma3s(hvHc + arow*SE, hvLc + arow*SE, 32 + ofk, fvH[1].v, fvL[1].v, vH, vLa, vLb);
        mfma3s(heHn + ie0*SE, heLn + ie0*SE, ofk,      fvH[4].v, fvL[4].v, vH, vLa, vLb);
        mfma3s(heHn + ie0*SE, heLn + ie0*SE, 32 + ofk, fvH[5].v, fvL[5].v, vH, vLa, vLb);
        mfma3s(heHn + ie1*SE, heLn + ie1*SE, ofk,      fvH[4].v, fvL[4].v, vH, vLa, vLb);
        mfma3s(heHn + ie1*SE, heLn + ie1*SE, 32 + ofk, fvH[5].v, fvL[5].v, vH, vLa, vLb);
        mfma3s(heHn + ie2*SE, heLn + ie2*SE, ofk,      fvH[4].v, fvL[4].v, vH2, vLa2, vLb2);
        mfma3s(heHn + ie2*SE, heLn + ie2*SE, 32 + ofk, fvH[5].v, fvL[5].v, vH2, vLa2, vLb2);
        mfma3s(heHn + ie3*SE, heLn + ie3*SE, ofk,      fvH[4].v, fvL[4].v, vH2, vLa2, vLb2);
        mfma3s(heHn + ie3*SE, heLn + ie3*SE, 32 + ofk, fvH[5].v, fvL[5].v, vH2, vLa2, vLb2);
        mfma3s(huH, huL, ofk,      fvH[6].v, fvL[6].v, vH2, vLa2, vLb2);
        mfma3s(huH, huL, 32 + ofk, fvH[7].v, fvL[7].v, vH2, vLa2, vLb2);

        if (tid < D)   // hebar reduce (readers are post-C), under the MFMA block
            hebar[tid] = parte[0][tid] + parte[1][tid] + parte[2][tid] + parte[3][tid];

        float outv2[4]; float ps2 = 0.f;
        #pragma unroll
        for (int r = 0; r < 4; ++r) {
            float t = fast_tanh((vH[r] + vH2[r]) + (vLa[r] + vLa2[r]) + (vLb[r] + vLb2[r]));
            outv2[r] = t; ps2 += t;
        }
        ps2 += __shfl_xor(ps2, 16, 64); ps2 += __shfl_xor(ps2, 32, 64);
        #pragma unroll
        for (int r = 0; r < 4; ++r) {
            int g = mt2 * 16 + kb * 4 + r;
            split2(outv2[r], hvH[nxt][g * SE + col], hvL[nxt][g * SE + col]);
        }
        if (kb == 0) part2[mt2][col] = ps2;
        __syncthreads();                                           // C: hv' + part2 ready

        // ---- phi_u partials: wave w owns K rows [w*32, w*32+32) ----
        {
            const int b  = w >> 1;             // source block (wave-uniform)
            const int k0 = (w & 1) * 32;
            float s = 0.f;
            #pragma unroll
            for (int kk = 0; kk < 32; ++kk) {
                int k = k0 + kk;
                float x = (b == 0) ? huF[k] : (b == 1) ? hu0F[k]
                        : (b == 2) ? hebar[k] : (part2[0][k] + part2[1][k]);
                s += x * wpu_reg[kk];
            }
            phiu_part[w][lane] = s;
        }
        __syncthreads();                                           // D: phiu_part ready
        cur = nxt;                             // hu finalize deferred to next iter
    }
}

extern "C" void kernel_launch(void* const* d_in, const int* in_sizes, int n_in,
                              void* d_out, int out_size, void* d_ws, size_t ws_size,
                              hipStream_t stream) {
    const float* atoms = (const float*)d_in[0];
    const float* adj   = (const float*)d_in[1];
    const int*   left  = (const int*)  d_in[2];
    const int*   right = (const int*)  d_in[3];
    const float* Wfe = (const float*)d_in[6];
    const float* bfe = (const float*)d_in[7];
    const float* Wfv = (const float*)d_in[8];
    const float* bfv = (const float*)d_in[9];
    const float* Wfu = (const float*)d_in[10];
    const float* bfu = (const float*)d_in[11];
    const float* Wpe = (const float*)d_in[12];
    const float* bpe = (const float*)d_in[13];
    const float* Wpv = (const float*)d_in[14];
    const float* bpv = (const float*)d_in[15];
    const float* Wpu = (const float*)d_in[16];
    const float* bpu = (const float*)d_in[17];

    graphnet_kernel<<<dim3(NMOLS), dim3(512), 0, stream>>>(
        atoms, adj, left, right,
        Wfe, bfe, Wfv, bfv, Wfu, bfu,
        Wpe, bpe, Wpv, bpv, Wpu, bpu,
        (float*)d_out);
}